// Round 1
// baseline (482.269 us; speedup 1.0000x reference)
//
#include <hip/hip_runtime.h>
#include <hip/hip_bf16.h>

#define DIM 768
#define NB 16
#define NPOS 4096
#define HEADS 12

typedef __attribute__((ext_vector_type(4))) float f32x4;
typedef __attribute__((ext_vector_type(8))) short s16x8;
typedef __attribute__((ext_vector_type(4))) unsigned short u16x4;

static __device__ __forceinline__ unsigned short f2bf(float f) {
  __hip_bfloat16 h = __float2bfloat16(f);
  unsigned short u; __builtin_memcpy(&u, &h, 2); return u;
}

// ---------------- BN path ----------------

// per (b,c): sum and sumsq over n=4096
__global__ __launch_bounds__(128) void sums_kernel(const float* __restrict__ x,
                                                   float* __restrict__ sum_bc,
                                                   float* __restrict__ sumsq_bc) {
  int bc = blockIdx.x;  // b*DIM + c
  const float4* p = (const float4*)(x + (size_t)bc * NPOS);
  int t = threadIdx.x;
  float s = 0.f, ss = 0.f;
  for (int i = t; i < NPOS / 4; i += 128) {
    float4 v = p[i];
    s  += v.x + v.y + v.z + v.w;
    ss += v.x * v.x + v.y * v.y + v.z * v.z + v.w * v.w;
  }
  for (int off = 32; off; off >>= 1) { s += __shfl_down(s, off); ss += __shfl_down(ss, off); }
  __shared__ float red[4];
  int lane = t & 63, w = t >> 6;
  if (lane == 0) { red[w] = s; red[2 + w] = ss; }
  __syncthreads();
  if (t == 0) { sum_bc[bc] = red[0] + red[1]; sumsq_bc[bc] = red[2] + red[3]; }
}

__global__ void finalize_kernel(const float* __restrict__ sum_bc, const float* __restrict__ sumsq_bc,
                                const float* __restrict__ gamma, const float* __restrict__ beta,
                                float* __restrict__ chanScale, float* __restrict__ chanShift) {
  int c = blockIdx.x * blockDim.x + threadIdx.x;
  if (c >= DIM) return;
  float s = 0.f, ss = 0.f;
  for (int b = 0; b < NB; b++) { s += sum_bc[b * DIM + c]; ss += sumsq_bc[b * DIM + c]; }
  const float invn = 1.f / ((float)NB * (float)NPOS);
  float mean = s * invn;
  float var  = ss * invn - mean * mean;
  float rstd = rsqrtf(var + 1e-5f);
  float a = rstd * gamma[c];
  chanScale[c] = a;
  chanShift[c] = beta[c] - mean * a;
}

__global__ __launch_bounds__(256) void bn_kernel(const float* __restrict__ x,
                                                 const float* __restrict__ chanScale,
                                                 const float* __restrict__ chanShift,
                                                 float* __restrict__ out) {
  const size_t n4 = (size_t)NB * DIM * NPOS / 4;
  const float4* x4 = (const float4*)x;
  float4* o4 = (float4*)out;
  for (size_t i = (size_t)blockIdx.x * blockDim.x + threadIdx.x; i < n4;
       i += (size_t)gridDim.x * blockDim.x) {
    float4 v = x4[i];
    int c = (int)((i >> 10) % DIM);   // 1024 float4 per (b,c) plane
    float a = chanScale[c], sh = chanShift[c];
    v.x = fmaxf(fmaf(v.x, a, sh), 0.f);
    v.y = fmaxf(fmaf(v.y, a, sh), 0.f);
    v.z = fmaxf(fmaf(v.z, a, sh), 0.f);
    v.w = fmaxf(fmaf(v.w, a, sh), 0.f);
    o4[i] = v;
  }
}

// ---------------- rank-1 correction vectors: t[b][r] = W[r,:]·s_b ----------------

__global__ __launch_bounds__(64) void tvec_kernel(const float* __restrict__ W,
                                                  const float* __restrict__ sum_bc,
                                                  float* __restrict__ tvec) {
  int r = blockIdx.x;   // 0..1535
  int b = blockIdx.y;
  int lane = threadIdx.x;
  const float* wr = W + (size_t)r * DIM;
  const float* sb = sum_bc + (size_t)b * DIM;
  float s = 0.f;
  for (int c = lane; c < DIM; c += 64) s += wr[c] * sb[c];
  for (int off = 32; off; off >>= 1) s += __shfl_down(s, off);
  if (lane == 0) tvec[(size_t)b * 1536 + r] = s;
}

// ---------------- generic C = A · B^T (rows of B), bf16 MFMA, 128x128 tile ----------------
// C[m][n] = sum_k A[m][k]*B[n][k].  A,B fp32 row-major; converted to bf16 during LDS staging.
// 256 threads = 4 waves (2x2), each wave 64x64 via 4x4 frags of mfma_f32_16x16x32_bf16.

#define LDT 40  // padded LDS row stride in shorts (80B -> bank spread, 16B-aligned frags)

__global__ __launch_bounds__(256) void gemm_bt_kernel(
    const float* __restrict__ A, long long strideA,
    const float* __restrict__ B, long long strideB,
    float* __restrict__ C, long long strideC,
    int lda, int ldb, int ldc, int K) {
  __shared__ __align__(16) unsigned short As[128 * LDT];
  __shared__ __align__(16) unsigned short Bs[128 * LDT];
  int bz = blockIdx.z;
  const float* Ab = A + (size_t)bz * strideA;
  const float* Bb = B + (size_t)bz * strideB;
  float* Cb = C + (size_t)bz * strideC;
  int ib = blockIdx.x * 128, jb = blockIdx.y * 128;

  int t = threadIdx.x, lane = t & 63, w = t >> 6;
  int wr = (w >> 1) * 64, wc = (w & 1) * 64;
  int fr = lane & 15, fk = (lane >> 4) * 8;
  int srow = t >> 3, sf4 = t & 7;   // staging: 32 rows x 8 float4 per pass

  f32x4 acc[4][4];
#pragma unroll
  for (int m = 0; m < 4; m++)
#pragma unroll
    for (int n = 0; n < 4; n++) acc[m][n] = (f32x4){0.f, 0.f, 0.f, 0.f};

  for (int k0 = 0; k0 < K; k0 += 32) {
    __syncthreads();
#pragma unroll
    for (int p = 0; p < 4; p++) {
      int r = srow + 32 * p;
      float4 va = *(const float4*)(Ab + (size_t)(ib + r) * lda + k0 + sf4 * 4);
      float4 vb = *(const float4*)(Bb + (size_t)(jb + r) * ldb + k0 + sf4 * 4);
      u16x4 ha = {f2bf(va.x), f2bf(va.y), f2bf(va.z), f2bf(va.w)};
      u16x4 hb = {f2bf(vb.x), f2bf(vb.y), f2bf(vb.z), f2bf(vb.w)};
      *(u16x4*)&As[r * LDT + sf4 * 4] = ha;
      *(u16x4*)&Bs[r * LDT + sf4 * 4] = hb;
    }
    __syncthreads();
    s16x8 af[4], bfv[4];
#pragma unroll
    for (int m = 0; m < 4; m++) af[m] = *(s16x8*)&As[(wr + m * 16 + fr) * LDT + fk];
#pragma unroll
    for (int n = 0; n < 4; n++) bfv[n] = *(s16x8*)&Bs[(wc + n * 16 + fr) * LDT + fk];
#pragma unroll
    for (int m = 0; m < 4; m++)
#pragma unroll
      for (int n = 0; n < 4; n++)
        acc[m][n] = __builtin_amdgcn_mfma_f32_16x16x32_bf16(af[m], bfv[n], acc[m][n], 0, 0, 0);
  }

  int rbase = (lane >> 4) * 4;
#pragma unroll
  for (int m = 0; m < 4; m++)
#pragma unroll
    for (int n = 0; n < 4; n++)
#pragma unroll
      for (int r = 0; r < 4; r++) {
        int row = ib + wr + m * 16 + rbase + r;
        int col = jb + wc + n * 16 + fr;
        Cb[(size_t)row * ldc + col] = acc[m][n][r];
      }
}

// ---------------- per-(b,h): attn = softmax(sign*sqrt(|S*(P·Wk^T + rank1)|+eps)) ----------------

__global__ __launch_bounds__(256) void attn_kernel(const float* __restrict__ P,
                                                   const float* __restrict__ W,
                                                   const float* __restrict__ bias,
                                                   const float* __restrict__ tvec,
                                                   float* __restrict__ outAttn) {
  int h = blockIdx.x, b = blockIdx.y;
  __shared__ __align__(16) unsigned short As[64 * LDT];
  __shared__ __align__(16) unsigned short Bs[64 * LDT];
  __shared__ float sm[64 * 65];
  const float* Pb = P + ((size_t)b * DIM + h * 64) * DIM;
  const float* Wk = W + ((size_t)(DIM + h * 64)) * DIM;

  int t = threadIdx.x, lane = t & 63, w = t >> 6;
  int fr = lane & 15, fk = (lane >> 4) * 8;
  int half = t >> 7;          // 0 -> stage A(P rows), 1 -> stage B(Wk rows)
  int tt = t & 127;
  int srow = tt >> 1, sf4b = (tt & 1) * 4;  // row 0..63, 4 float4 (16 floats) each
  const float* src = half ? Wk : Pb;
  unsigned short* dst = half ? Bs : As;

  f32x4 acc[4];
#pragma unroll
  for (int m = 0; m < 4; m++) acc[m] = (f32x4){0.f, 0.f, 0.f, 0.f};

  for (int k0 = 0; k0 < DIM; k0 += 32) {
    __syncthreads();
    const float4* sp = (const float4*)(src + (size_t)srow * DIM + k0) + sf4b;
    unsigned short* dp = dst + srow * LDT + sf4b * 4;
#pragma unroll
    for (int q = 0; q < 4; q++) {
      float4 v = sp[q];
      u16x4 hv = {f2bf(v.x), f2bf(v.y), f2bf(v.z), f2bf(v.w)};
      *(u16x4*)(dp + q * 4) = hv;
    }
    __syncthreads();
    s16x8 bfr = *(s16x8*)&Bs[(w * 16 + fr) * LDT + fk];
#pragma unroll
    for (int m = 0; m < 4; m++) {
      s16x8 afm = *(s16x8*)&As[(m * 16 + fr) * LDT + fk];
      acc[m] = __builtin_amdgcn_mfma_f32_16x16x32_bf16(afm, bfr, acc[m], 0, 0, 0);
    }
  }

  const float* tq = tvec + (size_t)b * 1536 + h * 64;
  const float* tk = tq + DIM;
  const float* bq = bias + h * 64;
  const float* bk = bias + DIM + h * 64;
  int e = w * 16 + fr;
  float bke = bk[e], tke = tk[e];
  int rbase = (lane >> 4) * 4;
#pragma unroll
  for (int m = 0; m < 4; m++)
#pragma unroll
    for (int r = 0; r < 4; r++) {
      int d = m * 16 + rbase + r;
      float bqd = bq[d];
      float raw = acc[m][r] + bqd * tke + bke * tq[d] + 4096.f * bqd * bke;
      float val = 0.125f * raw;  // SCALE = 64^-0.5
      float aa = fabsf(val);
      float sq = sqrtf(aa + 1e-5f);
      float tv = val > 0.f ? sq : (val < 0.f ? -sq : 0.f);
      sm[d * 65 + e] = tv;
    }
  __syncthreads();
  if (t < 64) {
    int d = t;
    float mx = -1e30f;
    for (int e2 = 0; e2 < 64; e2++) mx = fmaxf(mx, sm[d * 65 + e2]);
    float s = 0.f;
    for (int e2 = 0; e2 < 64; e2++) s += __expf(sm[d * 65 + e2] - mx);
    float inv = 1.f / s;
    float* o = outAttn + (((size_t)b * HEADS + h) * 64 + d) * 64;
    for (int e2 = 0; e2 < 64; e2++) o[e2] = __expf(sm[d * 65 + e2] - mx) * inv;
  }
}

// ---------------- launch ----------------

extern "C" void kernel_launch(void* const* d_in, const int* in_sizes, int n_in,
                              void* d_out, int out_size, void* d_ws, size_t ws_size,
                              hipStream_t stream) {
  const float* x     = (const float*)d_in[0];
  const float* qkv_w = (const float*)d_in[1];
  const float* qkv_b = (const float*)d_in[2];
  const float* gamma = (const float*)d_in[3];
  const float* beta  = (const float*)d_in[4];
  float* out = (float*)d_out;
  float* ws  = (float*)d_ws;

  // workspace layout (floats): total 18,925,568 (75.7 MB)
  float* sum_bc    = ws;                       // 16*768
  float* sumsq_bc  = ws + 12288;               // 16*768
  float* chanScale = ws + 24576;               // 768
  float* chanShift = ws + 25344;               // 768
  float* tvec      = ws + 26112;               // 16*1536
  float* G         = ws + 51200;               // 16*768*768
  float* P         = ws + 51200 + 9437184;     // 16*768*768

  sums_kernel<<<NB * DIM, 128, 0, stream>>>(x, sum_bc, sumsq_bc);
  finalize_kernel<<<3, 256, 0, stream>>>(sum_bc, sumsq_bc, gamma, beta, chanScale, chanShift);
  bn_kernel<<<2048, 256, 0, stream>>>(x, chanScale, chanShift, out);
  tvec_kernel<<<dim3(2 * DIM, NB), 64, 0, stream>>>(qkv_w, sum_bc, tvec);
  // G_b = X_b X_b^T   (M=N=768, K=4096)
  gemm_bt_kernel<<<dim3(6, 6, NB), 256, 0, stream>>>(
      x, (long long)DIM * NPOS, x, (long long)DIM * NPOS, G, (long long)DIM * DIM,
      NPOS, NPOS, DIM, NPOS);
  // P_b = Wq · G_b    (G symmetric -> B rows = G rows; M=N=K=768)
  gemm_bt_kernel<<<dim3(6, 6, NB), 256, 0, stream>>>(
      qkv_w, 0LL, G, (long long)DIM * DIM, P, (long long)DIM * DIM,
      DIM, DIM, DIM, DIM);
  attn_kernel<<<dim3(HEADS, NB), 256, 0, stream>>>(P, qkv_w, qkv_b, tvec,
                                                   out + (size_t)NB * DIM * NPOS);
}

// Round 2
// 313.617 us; speedup vs baseline: 1.5378x; 1.5378x over previous
//
#include <hip/hip_runtime.h>
#include <hip/hip_bf16.h>

#define DIM 768
#define NB 16
#define NPOS 4096
#define HEADS 12

typedef unsigned short u16;
typedef __attribute__((ext_vector_type(4))) float f32x4;
typedef __attribute__((ext_vector_type(8))) short s16x8;
typedef __attribute__((ext_vector_type(4))) u16 u16x4;

static __device__ __forceinline__ u16 f2bf(float f) {
  __hip_bfloat16 h = __float2bfloat16(f);
  u16 u; __builtin_memcpy(&u, &h, 2); return u;
}

// async global->LDS, 16B per lane; LDS dest = wave-uniform base + lane*16
static __device__ __forceinline__ void load_lds16(const void* g, void* l) {
  __builtin_amdgcn_global_load_lds(
      (const __attribute__((address_space(1))) unsigned int*)g,
      (__attribute__((address_space(3))) unsigned int*)l, 16, 0, 0);
}

// LDS tile layout: [rows][64 bf16] linear rows of 128B = 8 slots of 16B.
// slot is XOR-swizzled by (row&7); staging pre-swizzles the GLOBAL source.
static __device__ __forceinline__ int lds_idx(int row, int slotf) {
  return row * 64 + (((slotf) ^ (row & 7)) << 3);   // ushort units
}

// ---------------- BN path + fused cast to bf16 ----------------

__global__ __launch_bounds__(128) void sums_cast_kernel(const float* __restrict__ x,
                                                        float* __restrict__ sum_bc,
                                                        float* __restrict__ sumsq_bc,
                                                        u16* __restrict__ Xb) {
  int bc = blockIdx.x;  // b*DIM + c
  const float4* p = (const float4*)(x + (size_t)bc * NPOS);
  u16x4* ob = (u16x4*)(Xb + (size_t)bc * NPOS);
  int t = threadIdx.x;
  float s = 0.f, ss = 0.f;
  for (int i = t; i < NPOS / 4; i += 128) {
    float4 v = p[i];
    s  += v.x + v.y + v.z + v.w;
    ss += v.x * v.x + v.y * v.y + v.z * v.z + v.w * v.w;
    u16x4 hv = {f2bf(v.x), f2bf(v.y), f2bf(v.z), f2bf(v.w)};
    ob[i] = hv;
  }
  for (int off = 32; off; off >>= 1) { s += __shfl_down(s, off); ss += __shfl_down(ss, off); }
  __shared__ float red[4];
  int lane = t & 63, w = t >> 6;
  if (lane == 0) { red[w] = s; red[2 + w] = ss; }
  __syncthreads();
  if (t == 0) { sum_bc[bc] = red[0] + red[1]; sumsq_bc[bc] = red[2] + red[3]; }
}

__global__ void finalize_kernel(const float* __restrict__ sum_bc, const float* __restrict__ sumsq_bc,
                                const float* __restrict__ gamma, const float* __restrict__ beta,
                                float* __restrict__ chanScale, float* __restrict__ chanShift) {
  int c = blockIdx.x * blockDim.x + threadIdx.x;
  if (c >= DIM) return;
  float s = 0.f, ss = 0.f;
  for (int b = 0; b < NB; b++) { s += sum_bc[b * DIM + c]; ss += sumsq_bc[b * DIM + c]; }
  const float invn = 1.f / ((float)NB * (float)NPOS);
  float mean = s * invn;
  float var  = ss * invn - mean * mean;
  float rstd = rsqrtf(var + 1e-5f);
  float a = rstd * gamma[c];
  chanScale[c] = a;
  chanShift[c] = beta[c] - mean * a;
}

__global__ __launch_bounds__(256) void bn_kernel(const float* __restrict__ x,
                                                 const float* __restrict__ chanScale,
                                                 const float* __restrict__ chanShift,
                                                 float* __restrict__ out) {
  const size_t n4 = (size_t)NB * DIM * NPOS / 4;
  const float4* x4 = (const float4*)x;
  float4* o4 = (float4*)out;
  for (size_t i = (size_t)blockIdx.x * blockDim.x + threadIdx.x; i < n4;
       i += (size_t)gridDim.x * blockDim.x) {
    float4 v = x4[i];
    int c = (int)((i >> 10) % DIM);
    float a = chanScale[c], sh = chanShift[c];
    v.x = fmaxf(fmaf(v.x, a, sh), 0.f);
    v.y = fmaxf(fmaf(v.y, a, sh), 0.f);
    v.z = fmaxf(fmaf(v.z, a, sh), 0.f);
    v.w = fmaxf(fmaf(v.w, a, sh), 0.f);
    o4[i] = v;
  }
}

// ------------- tvec (t[b][r] = W[r,:]·s_b) + fused cast of W rows 0..1535 -------------

__global__ __launch_bounds__(64) void tvecw_kernel(const float* __restrict__ W,
                                                   const float* __restrict__ sum_bc,
                                                   float* __restrict__ tvec,
                                                   u16* __restrict__ Wb) {
  int r = blockIdx.x;   // 0..1535
  int lane = threadIdx.x;
  const float* wr = W + (size_t)r * DIM;
  float acc[NB];
#pragma unroll
  for (int b = 0; b < NB; b++) acc[b] = 0.f;
#pragma unroll
  for (int j = 0; j < DIM / 64; j++) {
    int c = lane + j * 64;
    float wv = wr[c];
    Wb[(size_t)r * DIM + c] = f2bf(wv);
#pragma unroll
    for (int b = 0; b < NB; b++) acc[b] += wv * sum_bc[b * DIM + c];
  }
#pragma unroll
  for (int b = 0; b < NB; b++) {
    float v = acc[b];
    for (int off = 32; off; off >>= 1) v += __shfl_down(v, off);
    if (lane == 0) tvec[(size_t)b * 1536 + r] = v;
  }
}

// ---------------- bf16 GEMM  C = A · B^T (rows of B), 128x128 tile, BK=64 ----------------
// SYMM: blockIdx.x enumerates tile pairs (ti<=tj); writes C and C^T (bf16 out).

template <bool SYMM>
__global__ __launch_bounds__(256) void gemm_kernel(
    const u16* __restrict__ A, long long strideA,
    const u16* __restrict__ B, long long strideB,
    u16* __restrict__ C, long long strideC,
    int lda, int ldb, int ldc, int K) {
  __shared__ __align__(16) u16 As[128 * 64];
  __shared__ __align__(16) u16 Bs[128 * 64];

  int ti, tj, bz;
  if (SYMM) {
    bz = blockIdx.y;
    int idx = blockIdx.x, rem = 6;
    ti = 0;
    while (idx >= rem) { idx -= rem; ti++; rem--; }
    tj = ti + idx;
  } else {
    ti = blockIdx.x; tj = blockIdx.y; bz = blockIdx.z;
  }
  const u16* Ab = A + (size_t)bz * strideA;
  const u16* Bb = B + (size_t)bz * strideB;
  u16* Cb = C + (size_t)bz * strideC;
  int ib = ti * 128, jb = tj * 128;

  int t = threadIdx.x, lane = t & 63, w = t >> 6;
  int wr = (w >> 1) * 64, wc = (w & 1) * 64;
  int fr = lane & 15, q4 = lane >> 4;
  int srow = lane >> 3;                 // 0..7 row within 8-row issue group
  int sslot = (lane & 7) ^ srow;        // pre-swizzled global slot

  f32x4 acc[4][4];
#pragma unroll
  for (int m = 0; m < 4; m++)
#pragma unroll
    for (int n = 0; n < 4; n++) acc[m][n] = (f32x4){0.f, 0.f, 0.f, 0.f};

  for (int k0 = 0; k0 < K; k0 += 64) {
    // stage 128x64 bf16 of A and B via global_load_lds (linear LDS, swizzled source)
#pragma unroll
    for (int i = 0; i < 4; i++) {
      int q = w * 4 + i;                // wave-issue 0..15, 8 rows each
      int row = q * 8 + srow;
      load_lds16(Ab + (size_t)(ib + row) * lda + k0 + sslot * 8, (char*)As + q * 1024);
      load_lds16(Bb + (size_t)(jb + row) * ldb + k0 + sslot * 8, (char*)Bs + q * 1024);
    }
    __syncthreads();   // compiler drains vmcnt before barrier
#pragma unroll
    for (int kk = 0; kk < 2; kk++) {
      int sbase = kk * 4 + q4;
      s16x8 af[4], bfv[4];
#pragma unroll
      for (int m = 0; m < 4; m++) af[m] = *(const s16x8*)&As[lds_idx(wr + m * 16 + fr, sbase)];
#pragma unroll
      for (int n = 0; n < 4; n++) bfv[n] = *(const s16x8*)&Bs[lds_idx(wc + n * 16 + fr, sbase)];
#pragma unroll
      for (int m = 0; m < 4; m++)
#pragma unroll
        for (int n = 0; n < 4; n++)
          acc[m][n] = __builtin_amdgcn_mfma_f32_16x16x32_bf16(af[m], bfv[n], acc[m][n], 0, 0, 0);
    }
    __syncthreads();
  }

  int rbase = q4 * 4;
#pragma unroll
  for (int m = 0; m < 4; m++)
#pragma unroll
    for (int n = 0; n < 4; n++)
#pragma unroll
      for (int r = 0; r < 4; r++) {
        int row = ib + wr + m * 16 + rbase + r;
        int col = jb + wc + n * 16 + fr;
        u16 v = f2bf(acc[m][n][r]);
        Cb[(size_t)row * ldc + col] = v;
        if (SYMM && ti != tj) Cb[(size_t)col * ldc + row] = v;
      }
}

// ---------- per-(b,h): attn = softmax(sign*sqrt(|S*(P·Wk^T + rank1)|+eps)) ----------

__global__ __launch_bounds__(256) void attn_kernel(const u16* __restrict__ Pb,
                                                   const u16* __restrict__ Wb,
                                                   const float* __restrict__ bias,
                                                   const float* __restrict__ tvec,
                                                   float* __restrict__ outAttn) {
  int h = blockIdx.x, b = blockIdx.y;
  __shared__ __align__(16) u16 As[64 * 64];
  __shared__ __align__(16) u16 Bs[64 * 64];
  __shared__ float sm[64 * 65];
  const u16* Pa = Pb + ((size_t)b * DIM + h * 64) * DIM;
  const u16* Wk = Wb + (size_t)(DIM + h * 64) * DIM;

  int t = threadIdx.x, lane = t & 63, w = t >> 6;
  int fr = lane & 15, q4 = lane >> 4;
  int srow = lane >> 3;
  int sslot = (lane & 7) ^ srow;

  f32x4 acc[4];
#pragma unroll
  for (int n = 0; n < 4; n++) acc[n] = (f32x4){0.f, 0.f, 0.f, 0.f};

  for (int k0 = 0; k0 < DIM; k0 += 64) {
#pragma unroll
    for (int i = 0; i < 2; i++) {
      int q = w * 2 + i;                // 0..7, 8 rows each -> 64 rows
      int row = q * 8 + srow;
      load_lds16(Pa + (size_t)row * DIM + k0 + sslot * 8, (char*)As + q * 1024);
      load_lds16(Wk + (size_t)row * DIM + k0 + sslot * 8, (char*)Bs + q * 1024);
    }
    __syncthreads();
#pragma unroll
    for (int kk = 0; kk < 2; kk++) {
      int sbase = kk * 4 + q4;
      s16x8 af = *(const s16x8*)&As[lds_idx(w * 16 + fr, sbase)];
#pragma unroll
      for (int n = 0; n < 4; n++) {
        s16x8 bfv = *(const s16x8*)&Bs[lds_idx(n * 16 + fr, sbase)];
        acc[n] = __builtin_amdgcn_mfma_f32_16x16x32_bf16(af, bfv, acc[n], 0, 0, 0);
      }
    }
    __syncthreads();
  }

  const float* tq = tvec + (size_t)b * 1536 + h * 64;
  const float* tk = tq + DIM;
  const float* bq = bias + h * 64;
  const float* bk = bias + DIM + h * 64;
  int rbase = q4 * 4;
#pragma unroll
  for (int n = 0; n < 4; n++) {
    int e = n * 16 + fr;
    float bke = bk[e], tke = tk[e];
#pragma unroll
    for (int r = 0; r < 4; r++) {
      int d = w * 16 + rbase + r;
      float bqd = bq[d];
      float raw = acc[n][r] + bqd * tke + bke * tq[d] + 4096.f * bqd * bke;
      float val = 0.125f * raw;  // SCALE = 64^-0.5
      float sq = sqrtf(fabsf(val) + 1e-5f);
      sm[d * 65 + e] = val > 0.f ? sq : (val < 0.f ? -sq : 0.f);
    }
  }
  __syncthreads();
  if (t < 64) {
    int d = t;
    float mx = -1e30f;
    for (int e2 = 0; e2 < 64; e2++) mx = fmaxf(mx, sm[d * 65 + e2]);
    float s = 0.f;
    for (int e2 = 0; e2 < 64; e2++) s += __expf(sm[d * 65 + e2] - mx);
    float inv = 1.f / s;
    float* o = outAttn + (((size_t)b * HEADS + h) * 64 + d) * 64;
    for (int e2 = 0; e2 < 64; e2++) o[e2] = __expf(sm[d * 65 + e2] - mx) * inv;
  }
}

// ---------------- launch ----------------

extern "C" void kernel_launch(void* const* d_in, const int* in_sizes, int n_in,
                              void* d_out, int out_size, void* d_ws, size_t ws_size,
                              hipStream_t stream) {
  const float* x     = (const float*)d_in[0];
  const float* qkv_w = (const float*)d_in[1];
  const float* qkv_b = (const float*)d_in[2];
  const float* gamma = (const float*)d_in[3];
  const float* beta  = (const float*)d_in[4];
  float* out = (float*)d_out;
  float* ws  = (float*)d_ws;

  // ws layout: fp32 smalls, then bf16 Wb / Gb / Pb.  Total ~40.3 MB.
  float* sum_bc    = ws;                        // 12288 f
  float* sumsq_bc  = ws + 12288;                // 12288 f
  float* chanScale = ws + 24576;                // 768
  float* chanShift = ws + 25344;                // 768
  float* tvec      = ws + 26112;                // 24576 f
  u16* Wb = (u16*)(ws + 50688);                               // 1536*768 bf16
  u16* Gb = (u16*)((char*)d_ws + 2562048);                    // 16*768*768 bf16
  u16* Pb = (u16*)((char*)d_ws + 2562048 + 18874368);         // 16*768*768 bf16

  // Xb (bf16 X, 100.7 MB) parks in d_out's y-region; bn_kernel overwrites it later.
  u16* Xb = (u16*)d_out;

  sums_cast_kernel<<<NB * DIM, 128, 0, stream>>>(x, sum_bc, sumsq_bc, Xb);
  finalize_kernel<<<3, 256, 0, stream>>>(sum_bc, sumsq_bc, gamma, beta, chanScale, chanShift);
  tvecw_kernel<<<2 * DIM, 64, 0, stream>>>(qkv_w, sum_bc, tvec, Wb);
  // G_b = X_b X_b^T  (symmetric: 21 tile pairs), bf16 out
  gemm_kernel<true><<<dim3(21, NB), 256, 0, stream>>>(
      Xb, (long long)DIM * NPOS, Xb, (long long)DIM * NPOS, Gb, (long long)DIM * DIM,
      NPOS, NPOS, DIM, NPOS);
  // now safe to overwrite d_out y-region
  bn_kernel<<<2048, 256, 0, stream>>>(x, chanScale, chanShift, out);
  // P_b = Wq · G_b  (G symmetric -> B rows = G rows)
  gemm_kernel<false><<<dim3(6, 6, NB), 256, 0, stream>>>(
      Wb, 0LL, Gb, (long long)DIM * DIM, Pb, (long long)DIM * DIM,
      DIM, DIM, DIM, DIM);
  attn_kernel<<<dim3(HEADS, NB), 256, 0, stream>>>(Pb, Wb, qkv_b, tvec,
                                                   out + (size_t)NB * DIM * NPOS);
}